// Round 1
// baseline (248.394 us; speedup 1.0000x reference)
//
#include <hip/hip_runtime.h>

// LstmCrf: linear-chain CRF loss. B=8192, S=512, C=9, fp32.
// R3 strategy: BIDIRECTIONAL exp-domain scan. Previous version ran 1024 waves
// (exactly 1 wave/SIMD on 256 CUs x 4 SIMDs) with a 512-step serial DPP
// recurrence -> latency-bound at ~2.4x the memory floor. Split each sequence:
//   fwd wave:  t = 0..255   (exact-init + t=1 state-8 peel, as verified in R2)
//   bwd wave:  t = 511..256 (beta recursion v' = E * (e_t (*) v), seeded with
//                            exp(T[s][END]-mT8); same vector cost as forward)
// Z = sum_s alpha_255[s] * beta_255[s]. 2048 waves = 2/SIMD, half chain length.
// Structural facts (from setup): T[START=0][:] = NEG  => E[0][j]=0 (fwd: state
// 0 never feeds anyone; bwd: v[0] becomes 0 after one step, harmless).
// T[:][END=8] = NEG => fwd q_8 = 0 for t>=2 (peeled), bwd state-8 source killed.
// Live chain is 8 states. Lane layout (16-lane DPP row = 2 batches): pos 0..15,
// batch = pos&1, state-slot s = pos>>1; row_ror:2m preserves parity.
// Weight tables built by rotating the state index through the SAME dpp op, so
// correctness does not depend on the ror direction convention.
// Backward weights are the TRANSPOSE: w_b[m] = exp(T[o][src(m)]).
// NOTE: assumes mask[b,0]==1 when any mask set (true here: mask is all ones).

#define CC 9
#define SS 512
#define NEGV (-10000.0f)
#define BLOCKT 256
#define HALF 256   // timesteps per direction
#define NCH 32     // chunks of 8 per direction
#define BPW 8      // batches per wave
#define BPB 16     // batches per block (2 fwd/bwd wave pairs)

template <int M>  // rotate by 2*M lanes within the 16-lane row (same parity)
__device__ __forceinline__ float rotf(float v) {
    return __int_as_float(__builtin_amdgcn_update_dpp(
        0, __float_as_int(v), 0x120 + 2 * M, 0xF, 0xF, false));
}
template <int M>
__device__ __forceinline__ int roti(int v) {
    return __builtin_amdgcn_update_dpp(0, v, 0x120 + 2 * M, 0xF, 0xF, false);
}

struct Chunk {
    float em[8];
    int lab[8];
    int msk[8];
    int labm1;  // label at t0-1 (backward chunks only)
};

struct St {
    float q, offset, goldtr, goldem;
    int len, prev;
};

__device__ __forceinline__ void load_chunk(Chunk& c, const float* emp,
                                           const int* labp, const int* mskp, int t0) {
#pragma unroll
    for (int k = 0; k < 8; ++k) c.em[k] = emp[(t0 + k) * CC];
    int4 l0 = *(const int4*)(labp + t0);
    int4 l1 = *(const int4*)(labp + t0 + 4);
    int4 m0 = *(const int4*)(mskp + t0);
    int4 m1 = *(const int4*)(mskp + t0 + 4);
    c.lab[0] = l0.x; c.lab[1] = l0.y; c.lab[2] = l0.z; c.lab[3] = l0.w;
    c.lab[4] = l1.x; c.lab[5] = l1.y; c.lab[6] = l1.z; c.lab[7] = l1.w;
    c.msk[0] = m0.x; c.msk[1] = m0.y; c.msk[2] = m0.z; c.msk[3] = m0.w;
    c.msk[4] = m1.x; c.msk[5] = m1.y; c.msk[6] = m1.z; c.msk[7] = m1.w;
}

__device__ __forceinline__ void load_chunk_b(Chunk& c, const float* emp,
                                             const int* labp, const int* mskp, int t0) {
    load_chunk(c, emp, labp, mskp, t0);
    c.labm1 = labp[t0 - 1];  // t0 >= 256 always, so t0-1 valid
}

__device__ __forceinline__ void renorm8(St& st, float& nq) {
    float mx = fmaxf(nq, rotf<1>(nq));
    mx = fmaxf(mx, rotf<2>(mx));
    mx = fmaxf(mx, rotf<4>(mx));
    nq *= __builtin_amdgcn_rcpf(mx);
    st.offset += __logf(mx);
}

// forward: alpha'[o] = (sum_src alpha[src] * exp(T[src][o])) * exp(em[o])
template <bool RENORM>
__device__ __forceinline__ void crf_step(St& st, float e, float em, int lab, int msk,
                                         float tv, const float* w, int o) {
    float q = st.q;
    float g1 = rotf<1>(q), g2 = rotf<2>(q), g3 = rotf<3>(q);
    float g4 = rotf<4>(q), g5 = rotf<5>(q), g6 = rotf<6>(q), g7 = rotf<7>(q);
    float s0 = q * w[0];
    float s1 = g1 * w[1];
    float s2 = g2 * w[2];
    s0 = fmaf(g3, w[3], s0);
    s1 = fmaf(g4, w[4], s1);
    s2 = fmaf(g5, w[5], s2);
    s0 = fmaf(g6, w[6], s0);
    s1 = fmaf(g7, w[7], s1);
    float ssum = s0 + (s1 + s2);
    bool m = (msk != 0);
    st.goldtr += m ? tv : 0.0f;
    st.goldem += (m && lab == o) ? em : 0.0f;
    st.len += m ? 1 : 0;
    float nq = m ? ssum * e : q;
    if (RENORM) renorm8(st, nq);
    st.q = nq;
}

// backward: beta'[o] = sum_src exp(T[o][src]) * (exp(em[src]) * beta[src])
// own-emission multiply happens BEFORE the cross-lane gather.
template <bool RENORM>
__device__ __forceinline__ void crf_step_b(St& st, float e, float em, int lab, int msk,
                                           float tv, const float* w, int o) {
    float q = st.q;
    float p = q * e;
    float g1 = rotf<1>(p), g2 = rotf<2>(p), g3 = rotf<3>(p);
    float g4 = rotf<4>(p), g5 = rotf<5>(p), g6 = rotf<6>(p), g7 = rotf<7>(p);
    float s0 = p * w[0];
    float s1 = g1 * w[1];
    float s2 = g2 * w[2];
    s0 = fmaf(g3, w[3], s0);
    s1 = fmaf(g4, w[4], s1);
    s2 = fmaf(g5, w[5], s2);
    s0 = fmaf(g6, w[6], s0);
    s1 = fmaf(g7, w[7], s1);
    float ssum = s0 + (s1 + s2);
    bool m = (msk != 0);
    st.goldtr += m ? tv : 0.0f;
    st.goldem += (m && lab == o) ? em : 0.0f;
    st.len += m ? 1 : 0;
    float nq = m ? ssum : q;
    if (RENORM) renorm8(st, nq);
    st.q = nq;
}

__device__ __forceinline__ void consume8(St& st, const Chunk& c, const float* Tl,
                                         const float* w, int o) {
    float tv[8];
    tv[0] = Tl[st.prev * CC + c.lab[0]];
#pragma unroll
    for (int k = 1; k < 8; ++k) tv[k] = Tl[c.lab[k - 1] * CC + c.lab[k]];
    st.prev = c.lab[7];
    float e[8];
#pragma unroll
    for (int k = 0; k < 8; ++k) e[k] = __expf(c.em[k]);  // hides tv LDS latency
    crf_step<true >(st, e[0], c.em[0], c.lab[0], c.msk[0], tv[0], w, o);
    crf_step<false>(st, e[1], c.em[1], c.lab[1], c.msk[1], tv[1], w, o);
    crf_step<false>(st, e[2], c.em[2], c.lab[2], c.msk[2], tv[2], w, o);
    crf_step<false>(st, e[3], c.em[3], c.lab[3], c.msk[3], tv[3], w, o);
    crf_step<true >(st, e[4], c.em[4], c.lab[4], c.msk[4], tv[4], w, o);
    crf_step<false>(st, e[5], c.em[5], c.lab[5], c.msk[5], tv[5], w, o);
    crf_step<false>(st, e[6], c.em[6], c.lab[6], c.msk[6], tv[6], w, o);
    crf_step<false>(st, e[7], c.em[7], c.lab[7], c.msk[7], tv[7], w, o);
}

// backward: process steps k = 7 down to 0 (decreasing t). tv[0] uses labm1.
__device__ __forceinline__ void consume8_b(St& st, const Chunk& c, const float* Tl,
                                           const float* w, int o) {
    float tv[8];
    tv[0] = Tl[c.labm1 * CC + c.lab[0]];
#pragma unroll
    for (int k = 1; k < 8; ++k) tv[k] = Tl[c.lab[k - 1] * CC + c.lab[k]];
    float e[8];
#pragma unroll
    for (int k = 0; k < 8; ++k) e[k] = __expf(c.em[k]);
    crf_step_b<true >(st, e[7], c.em[7], c.lab[7], c.msk[7], tv[7], w, o);
    crf_step_b<false>(st, e[6], c.em[6], c.lab[6], c.msk[6], tv[6], w, o);
    crf_step_b<false>(st, e[5], c.em[5], c.lab[5], c.msk[5], tv[5], w, o);
    crf_step_b<false>(st, e[4], c.em[4], c.lab[4], c.msk[4], tv[4], w, o);
    crf_step_b<true >(st, e[3], c.em[3], c.lab[3], c.msk[3], tv[3], w, o);
    crf_step_b<false>(st, e[2], c.em[2], c.lab[2], c.msk[2], tv[2], w, o);
    crf_step_b<false>(st, e[1], c.em[1], c.lab[1], c.msk[1], tv[1], w, o);
    crf_step_b<false>(st, e[0], c.em[0], c.lab[0], c.msk[0], tv[0], w, o);
}

__global__ __launch_bounds__(BLOCKT, 2) void crf_main(
    const float* __restrict__ emission, const float* __restrict__ transition,
    const int* __restrict__ labels, const int* __restrict__ mask,
    float* __restrict__ out, int B, float invB) {
    __shared__ float Tl[CC * CC];
    __shared__ float su[BPB][8];   // fwd alpha_255 (renormalized) per (batch,state)
    __shared__ float soff[BPB];    // fwd log-offset
    __shared__ float sgold[BPB];   // fwd gold partial (em + trans, t=0..255)
    __shared__ int slen[BPB];      // fwd mask count
    __shared__ float blocksum;
    int tid = threadIdx.x;
    if (tid == 0) blocksum = 0.0f;
    for (int i = tid; i < CC * CC; i += BLOCKT) Tl[i] = transition[i];
    __syncthreads();

    int lane = tid & 63, wv = tid >> 6;
    int pos = lane & 15, row = lane >> 4;
    int par = pos & 1, s = pos >> 1;   // state-slot 0..7
    int o = s;                         // output state this lane owns
    int isB = wv & 1;                  // odd waves run the backward half
    int lb = (wv >> 1) * BPW + row * 2 + par;   // local batch 0..15
    long batch = (long)blockIdx.x * BPB + lb;
    bool valid = batch < (long)B;
    size_t bidx = valid ? (size_t)batch : 0;

    // source state-slot per rotation (via the same dpp op => direction-proof)
    int ssrc[8];
    ssrc[0] = s;
    ssrc[1] = roti<1>(s); ssrc[2] = roti<2>(s); ssrc[3] = roti<3>(s);
    ssrc[4] = roti<4>(s); ssrc[5] = roti<5>(s); ssrc[6] = roti<6>(s);
    ssrc[7] = roti<7>(s);

    const float* emp = emission + bidx * (SS * CC) + o;
    const int* labp = labels + bidx * SS;
    const int* mskp = mask + bidx * SS;

    if (!isB) {
        // ---------------- FORWARD: t = 0 .. 255 ----------------
        float wmain[8], wf[8];
#pragma unroll
        for (int m = 0; m < 8; ++m) {
            int is_ = ssrc[m];
            wmain[m] = __expf(Tl[is_ * CC + o]);                 // E[0][o]=0 naturally
            wf[m] = __expf(Tl[(is_ == 0 ? 8 : is_) * CC + o]);   // slot0 = state 8 at t=1
        }

        // exact-init logsumexp: v = this lane's t=0 column (s==0 -> col 8), vref = col 1
        int colq = (s == 0) ? 8 : s;
        float v, vref;
        {
            float mx1 = Tl[colq], mx2 = Tl[1];  // i=0 term: init_0(=0) + T[0][col]
#pragma unroll
            for (int i = 1; i < CC; ++i) {
                mx1 = fmaxf(mx1, NEGV + Tl[i * CC + colq]);
                mx2 = fmaxf(mx2, NEGV + Tl[i * CC + 1]);
            }
            float a1 = __expf(Tl[colq] - mx1), a2 = __expf(Tl[1] - mx2);
#pragma unroll
            for (int i = 1; i < CC; ++i) {
                a1 += __expf(NEGV + Tl[i * CC + colq] - mx1);
                a2 += __expf(NEGV + Tl[i * CC + 1] - mx2);
            }
            v = mx1 + __logf(a1);
            vref = mx2 + __logf(a2);
        }
        float em8 = emission[bidx * (SS * CC) + 8];  // col 8 at t=0 (lane s==0's q init)

        Chunk A, Bc;
        load_chunk(A, emp, labp, mskp, 0);
        load_chunk(Bc, emp, labp, mskp, 8);

        St st;
        st.q = 0.f; st.offset = 0.f; st.goldtr = 0.f; st.goldem = 0.f;
        st.len = 0; st.prev = 0;

        // t=0: exact init
        {
            bool m0 = (A.msk[0] != 0);
            float em0q = (s == 0) ? em8 : A.em[0];
            st.q = m0 ? __expf(v + em0q - vref) : 0.0f;
            st.offset = m0 ? vref : 0.0f;
            st.goldtr = m0 ? Tl[A.lab[0]] : 0.0f;  // T[START][lab0]
            st.goldem = (m0 && A.lab[0] == o) ? A.em[0] : 0.0f;
            st.len = m0 ? 1 : 0;
        }
        // rest of chunk 0: t=1 peeled with wf (state-8 injection), then wmain
        {
            float tv[8];
#pragma unroll
            for (int k = 1; k < 8; ++k) tv[k] = Tl[A.lab[k - 1] * CC + A.lab[k]];
            st.prev = A.lab[7];
            float e[8];
#pragma unroll
            for (int k = 1; k < 8; ++k) e[k] = __expf(A.em[k]);
            crf_step<false>(st, e[1], A.em[1], A.lab[1], A.msk[1], tv[1], wf, o);
            crf_step<false>(st, e[2], A.em[2], A.lab[2], A.msk[2], tv[2], wmain, o);
            crf_step<false>(st, e[3], A.em[3], A.lab[3], A.msk[3], tv[3], wmain, o);
            crf_step<true >(st, e[4], A.em[4], A.lab[4], A.msk[4], tv[4], wmain, o);
            crf_step<false>(st, e[5], A.em[5], A.lab[5], A.msk[5], tv[5], wmain, o);
            crf_step<false>(st, e[6], A.em[6], A.lab[6], A.msk[6], tv[6], wmain, o);
            crf_step<false>(st, e[7], A.em[7], A.lab[7], A.msk[7], tv[7], wmain, o);
        }
        load_chunk(A, emp, labp, mskp, 16);

        for (int c = 1; c <= NCH - 3; c += 2) {
            consume8(st, Bc, Tl, wmain, o);
            load_chunk(Bc, emp, labp, mskp, (c + 2) * 8);
            consume8(st, A, Tl, wmain, o);
            if (c + 3 <= NCH - 1) load_chunk(A, emp, labp, mskp, (c + 3) * 8);
        }
        consume8(st, Bc, Tl, wmain, o);  // chunk NCH-1 (t=248..255)

        // publish alpha_255 + per-batch scalars for the paired backward wave
        su[lb][s] = st.q;
        float gpart = st.goldem + ((s == 0) ? st.goldtr : 0.0f);
        float sg = gpart + rotf<1>(gpart);
        sg = sg + rotf<2>(sg);
        sg = sg + rotf<4>(sg);
        if (s == 0) {
            soff[lb] = st.offset;
            sgold[lb] = sg;
            slen[lb] = st.len;
        }
    } else {
        // ---------------- BACKWARD: t = 511 .. 256 ----------------
        float wb[8];
#pragma unroll
        for (int m = 0; m < 8; ++m) wb[m] = __expf(Tl[o * CC + ssrc[m]]);  // transposed

        float mT8 = Tl[8];
#pragma unroll
        for (int i = 1; i < CC; ++i) mT8 = fmaxf(mT8, Tl[i * CC + 8]);

        St st;
        st.q = __expf(Tl[o * CC + 8] - mT8);  // beta seed exp(T[o][END]-mT8) (=1 here)
        st.offset = mT8;
        st.goldtr = 0.f; st.goldem = 0.f; st.len = 0; st.prev = 0;

        Chunk A, Bc;
        load_chunk_b(A, emp, labp, mskp, HALF + 8 * (NCH - 1));   // t=504..511
        load_chunk_b(Bc, emp, labp, mskp, HALF + 8 * (NCH - 2));  // t=496..503
        consume8_b(st, A, Tl, wb, o);                             // chunk 31
        load_chunk_b(A, emp, labp, mskp, HALF + 8 * (NCH - 3));

        for (int cc = NCH - 2; cc >= 2; cc -= 2) {
            consume8_b(st, Bc, Tl, wb, o);                        // chunk cc
            load_chunk_b(Bc, emp, labp, mskp, HALF + 8 * (cc - 2));
            consume8_b(st, A, Tl, wb, o);                         // chunk cc-1
            if (cc - 3 >= 0) load_chunk_b(A, emp, labp, mskp, HALF + 8 * (cc - 3));
        }
        consume8_b(st, Bc, Tl, wb, o);  // chunk 0 (t=256..263)
        // st.q = beta_255 (per-state, renormalized), st.offset includes mT8

        // stash backward state in registers; combine after the barrier
        // (fall through — combine below)
        // persist via local copies: the combine code reads st directly.
        __syncthreads();  // wait for fwd wave's LDS publish
        float u = su[lb][s];
        float prodv = u * st.q;
        float sw = prodv + rotf<1>(prodv);
        sw = sw + rotf<2>(sw);
        sw = sw + rotf<4>(sw);
        int lenT = slen[lb] + st.len;
        float gpart = st.goldem;
        if (s == 0) {
            int lastlab = (lenT > 0) ? labp[lenT - 1] : 0;
            gpart += st.goldtr + Tl[lastlab * CC + 8];  // + T[last][END]
        }
        float sg = gpart + rotf<1>(gpart);
        sg = sg + rotf<2>(sg);
        sg = sg + rotf<4>(sg);
        if (valid && s == 0) {
            float logZ = soff[lb] + st.offset + __logf(sw);
            float gold = sgold[lb] + sg;
            atomicAdd(&blocksum, (logZ - gold) * invB);
        }
    }
    if (!isB) __syncthreads();  // fwd waves: match the bwd wave's barrier
    __syncthreads();
    if (tid == 0) atomicAdd(out, blocksum);
}

extern "C" void kernel_launch(void* const* d_in, const int* in_sizes, int n_in,
                              void* d_out, int out_size, void* d_ws, size_t ws_size,
                              hipStream_t stream) {
    const float* emission = (const float*)d_in[0];
    const float* transition = (const float*)d_in[1];
    const int* labels = (const int*)d_in[2];
    const int* mask = (const int*)d_in[3];
    float* out = (float*)d_out;

    int B = in_sizes[2] / SS;
    float invB = 1.0f / (float)B;

    hipMemsetAsync(out, 0, sizeof(float) * out_size, stream);
    int nblocks = (B + BPB - 1) / BPB;
    crf_main<<<nblocks, BLOCKT, 0, stream>>>(emission, transition, labels, mask,
                                             out, B, invB);
}